// Round 1
// baseline (413.616 us; speedup 1.0000x reference)
//
#include <hip/hip_runtime.h>

// Winograd F(2x2,3x3) fused conv. B=8, C=64, K=64, H=W=130 -> out 8x64x128x128 fp32.
// Kernel 1: U[xy][c][k] = G w G^T   (16*64*64 fp32 = 256KB in d_ws)
// Kernel 2: fused input-transform + 16 xy-GEMMs + inverse transform + bias.

#define CC 8      // C chunk
#define NCH 8     // 64/CC
#define TN 4      // tile rows per block
#define TM 16     // tile cols per block  (4x16 = 64 tiles -> 8x32 output pixels)

__global__ void wg_u_kernel(const float* __restrict__ w, float* __restrict__ U) {
    int tid = blockIdx.x * blockDim.x + threadIdx.x;   // 4096 = K*C
    int k = tid & 63;
    int c = tid >> 6;
    if (c >= 64) return;
    const float* wp = w + (k * 64 + c) * 9;
    float g0 = wp[0], g1 = wp[1], g2 = wp[2];
    float g3 = wp[3], g4 = wp[4], g5 = wp[5];
    float g6 = wp[6], g7 = wp[7], g8 = wp[8];
    // t = G * w   (4x3)
    float t0[3] = { g0, g1, g2 };
    float t1[3] = { 0.5f*(g0+g3+g6), 0.5f*(g1+g4+g7), 0.5f*(g2+g5+g8) };
    float t2[3] = { 0.5f*(g0-g3+g6), 0.5f*(g1-g4+g7), 0.5f*(g2-g5+g8) };
    float t3[3] = { g6, g7, g8 };
    float* tr[4] = { t0, t1, t2, t3 };
    #pragma unroll
    for (int x = 0; x < 4; ++x) {
        float a = tr[x][0], b2 = tr[x][1], c2 = tr[x][2];
        float u0 = a;
        float u1 = 0.5f*(a + b2 + c2);
        float u2 = 0.5f*(a - b2 + c2);
        float u3 = c2;
        U[(x*4+0)*4096 + c*64 + k] = u0;
        U[(x*4+1)*4096 + c*64 + k] = u1;
        U[(x*4+2)*4096 + c*64 + k] = u2;
        U[(x*4+3)*4096 + c*64 + k] = u3;
    }
}

__global__ __launch_bounds__(1024) void wg_main(
    const float* __restrict__ x, const float* __restrict__ U,
    const float* __restrict__ bias, float* __restrict__ out)
{
    // 64KB static LDS: sU[16][CC][64] | sV[16][CC][64]; epilogue aliases sM[16][16][64]
    __shared__ float smem[16384];
    float* sU = smem;          // 8192 floats
    float* sV = smem + 8192;   // 8192 floats
    float* sM = smem;          // 16384 floats (epilogue)

    const int tid  = threadIdx.x;
    const int bx   = blockIdx.x;
    const int b    = bx >> 6;
    const int rr   = bx & 63;
    const int bh   = rr >> 2;          // 0..15
    const int bw   = rr & 3;           // 0..3
    const int h0   = bh * (TN * 2);    // input row origin
    const int w0   = bw * (TM * 2);    // input col origin

    const int wv   = tid >> 6;         // wave id: xy (gemm) / c_local (transform) / k_local (epi)
    const int lane = tid & 63;
    const int k0   = (lane >> 3) << 3; // gemm: 8-k group
    const int t0   = (lane & 7) << 3;  // gemm: 8-t group
    const int tn   = lane >> 4;        // tile row 0..3
    const int tm   = lane & 15;        // tile col 0..15

    // transform threads (tid<512): channel = ch*CC + wv, tile (tn,tm)
    const float* xbase = x + ((size_t)(b * 64 + wv) * 130 + (h0 + 2 * tn)) * 130 + (w0 + 2 * tm);

    // U staging: 8192 floats per chunk = 2048 float4 ; thread stores float4 #tid and #tid+1024
    const int u_idx0 = tid;
    const int u_idx1 = tid + 1024;
    const int ug0 = (u_idx0 >> 7) * 1024 + (u_idx0 & 127);  // global float4 idx (xy*1024 + off4)
    const int ug1 = (u_idx1 >> 7) * 1024 + (u_idx1 & 127);
    const float4* U4 = (const float4*)U;

    float acc[8][8];
    #pragma unroll
    for (int i = 0; i < 8; ++i)
        #pragma unroll
        for (int j = 0; j < 8; ++j) acc[i][j] = 0.0f;

    // prefetch regs (chunk 0)
    float4 uf0 = U4[ug0];
    float4 uf1 = U4[ug1];
    float2 dn[4][2];
    if (tid < 512) {
        #pragma unroll
        for (int i = 0; i < 4; ++i) {
            dn[i][0] = *(const float2*)(xbase + i * 130);
            dn[i][1] = *(const float2*)(xbase + i * 130 + 2);
        }
    }

    #pragma unroll 1
    for (int ch = 0; ch < NCH; ++ch) {
        __syncthreads();   // previous GEMM done reading sU/sV
        // stage U chunk
        ((float4*)sU)[u_idx0] = uf0;
        ((float4*)sU)[u_idx1] = uf1;
        // input transform: V = B^T d B
        if (tid < 512) {
            float d[4][4];
            #pragma unroll
            for (int i = 0; i < 4; ++i) {
                d[i][0] = dn[i][0].x; d[i][1] = dn[i][0].y;
                d[i][2] = dn[i][1].x; d[i][3] = dn[i][1].y;
            }
            float s0[4], s1[4], s2[4], s3[4];
            #pragma unroll
            for (int j = 0; j < 4; ++j) {
                s0[j] = d[0][j] - d[2][j];
                s1[j] = d[1][j] + d[2][j];
                s2[j] = d[2][j] - d[1][j];
                s3[j] = d[1][j] - d[3][j];
            }
            const int vo = wv * 64 + lane;   // c_local*64 + t
            #define VROW(X, R)                                  \
                sV[((X)*4+0)*512 + vo] = R[0] - R[2];           \
                sV[((X)*4+1)*512 + vo] = R[1] + R[2];           \
                sV[((X)*4+2)*512 + vo] = R[2] - R[1];           \
                sV[((X)*4+3)*512 + vo] = R[1] - R[3];
            VROW(0, s0) VROW(1, s1) VROW(2, s2) VROW(3, s3)
            #undef VROW
        }
        __syncthreads();
        // prefetch next chunk (overlaps GEMM)
        if (ch < NCH - 1) {
            uf0 = U4[ug0 + (ch + 1) * 128];
            uf1 = U4[ug1 + (ch + 1) * 128];
            if (tid < 512) {
                const float* xn = xbase + (size_t)(ch + 1) * CC * 16900;
                #pragma unroll
                for (int i = 0; i < 4; ++i) {
                    dn[i][0] = *(const float2*)(xn + i * 130);
                    dn[i][1] = *(const float2*)(xn + i * 130 + 2);
                }
            }
        }
        // GEMM: wave wv owns xy=wv; lane tile 8k x 8t
        const float* Ub = sU + wv * 512 + k0;
        const float* Vb = sV + wv * 512 + t0;
        #pragma unroll
        for (int c = 0; c < CC; ++c) {
            float4 ua = *(const float4*)(Ub + c * 64);
            float4 ub = *(const float4*)(Ub + c * 64 + 4);
            float4 va = *(const float4*)(Vb + c * 64);
            float4 vb = *(const float4*)(Vb + c * 64 + 4);
            float uu[8] = { ua.x, ua.y, ua.z, ua.w, ub.x, ub.y, ub.z, ub.w };
            float vv[8] = { va.x, va.y, va.z, va.w, vb.x, vb.y, vb.z, vb.w };
            #pragma unroll
            for (int i = 0; i < 8; ++i)
                #pragma unroll
                for (int j = 0; j < 8; ++j)
                    acc[i][j] = fmaf(uu[i], vv[j], acc[i][j]);
        }
    }

    // epilogue: Y = A^T M A + bias, k in chunks of 16 through sM
    const int g = lane >> 3;
    #pragma unroll 1
    for (int kc = 0; kc < 4; ++kc) {
        __syncthreads();   // sM free (last GEMM / previous kc readers done)
        if (g == 2 * kc || g == 2 * kc + 1) {
            const int kk0 = k0 - kc * 16;          // 0 or 8
            float* mp = sM + wv * 1024 + kk0 * 64 + t0;
            #pragma unroll
            for (int i = 0; i < 8; ++i) {
                *(float4*)(mp + i * 64)     = make_float4(acc[i][0], acc[i][1], acc[i][2], acc[i][3]);
                *(float4*)(mp + i * 64 + 4) = make_float4(acc[i][4], acc[i][5], acc[i][6], acc[i][7]);
            }
        }
        __syncthreads();
        // k = kc*16 + wv, tile t = lane
        float m[16];
        #pragma unroll
        for (int xy = 0; xy < 16; ++xy) m[xy] = sM[xy * 1024 + wv * 64 + lane];
        float p0[4], p1[4];
        #pragma unroll
        for (int y = 0; y < 4; ++y) {
            p0[y] = m[y] + m[4 + y] + m[8 + y];
            p1[y] = m[4 + y] - m[8 + y] - m[12 + y];
        }
        const int k = kc * 16 + wv;
        const float bv = bias[k];
        const float y00 = p0[0] + p0[1] + p0[2] + bv;
        const float y01 = p0[1] - p0[2] - p0[3] + bv;
        const float y10 = p1[0] + p1[1] + p1[2] + bv;
        const float y11 = p1[1] - p1[2] - p1[3] + bv;
        const int oh = (bh * TN + tn) * 2;
        const int ow = (bw * TM + tm) * 2;
        float* op = out + ((size_t)(b * 64 + k) * 128 + oh) * 128 + ow;
        *(float2*)op         = make_float2(y00, y01);
        *(float2*)(op + 128) = make_float2(y10, y11);
    }
}

extern "C" void kernel_launch(void* const* d_in, const int* in_sizes, int n_in,
                              void* d_out, int out_size, void* d_ws, size_t ws_size,
                              hipStream_t stream) {
    const float* x    = (const float*)d_in[0];
    const float* w    = (const float*)d_in[1];
    const float* bias = (const float*)d_in[2];
    float* out = (float*)d_out;
    float* U   = (float*)d_ws;   // 256 KB
    wg_u_kernel<<<16, 256, 0, stream>>>(w, U);
    wg_main<<<512, 1024, 0, stream>>>(x, U, bias, out);
}

// Round 3
// 155.927 us; speedup vs baseline: 2.6526x; 2.6526x over previous
//
#include <hip/hip_runtime.h>

// Winograd F(2x2,3x3) fused conv. B=8, C=64, K=64, H=W=130 -> out 8x64x128x128 fp32.
// Kernel 1: U[xy][c][k] = G w G^T   (16*64*64 fp32 = 256KB in d_ws)
// Kernel 2: fused input-transform + 16 xy-GEMMs + inverse transform + bias.
// R2: fix VGPR cap (64 -> 128 via __launch_bounds__(1024,4)); bound c-loop unroll
//     to stop load-hoisting re-spill. R1 spilled acc to scratch (WRITE_SIZE 900MB).
// R3: identical resubmit (R2 bench never ran: GPU acquisition timeout).

#define CC 8      // C chunk
#define NCH 8     // 64/CC
#define TN 4      // tile rows per block
#define TM 16     // tile cols per block  (4x16 = 64 tiles -> 8x32 output pixels)

__global__ void wg_u_kernel(const float* __restrict__ w, float* __restrict__ U) {
    int tid = blockIdx.x * blockDim.x + threadIdx.x;   // 4096 = K*C
    int k = tid & 63;
    int c = tid >> 6;
    if (c >= 64) return;
    const float* wp = w + (k * 64 + c) * 9;
    float g0 = wp[0], g1 = wp[1], g2 = wp[2];
    float g3 = wp[3], g4 = wp[4], g5 = wp[5];
    float g6 = wp[6], g7 = wp[7], g8 = wp[8];
    // t = G * w   (4x3)
    float t0[3] = { g0, g1, g2 };
    float t1[3] = { 0.5f*(g0+g3+g6), 0.5f*(g1+g4+g7), 0.5f*(g2+g5+g8) };
    float t2[3] = { 0.5f*(g0-g3+g6), 0.5f*(g1-g4+g7), 0.5f*(g2-g5+g8) };
    float t3[3] = { g6, g7, g8 };
    float* tr[4] = { t0, t1, t2, t3 };
    #pragma unroll
    for (int x = 0; x < 4; ++x) {
        float a = tr[x][0], b2 = tr[x][1], c2 = tr[x][2];
        float u0 = a;
        float u1 = 0.5f*(a + b2 + c2);
        float u2 = 0.5f*(a - b2 + c2);
        float u3 = c2;
        U[(x*4+0)*4096 + c*64 + k] = u0;
        U[(x*4+1)*4096 + c*64 + k] = u1;
        U[(x*4+2)*4096 + c*64 + k] = u2;
        U[(x*4+3)*4096 + c*64 + k] = u3;
    }
}

__global__ __launch_bounds__(1024, 4) void wg_main(
    const float* __restrict__ x, const float* __restrict__ U,
    const float* __restrict__ bias, float* __restrict__ out)
{
    // 64KB static LDS: sU[16][CC][64] | sV[16][CC][64]; epilogue aliases sM[16][16][64]
    __shared__ float smem[16384];
    float* sU = smem;          // 8192 floats
    float* sV = smem + 8192;   // 8192 floats
    float* sM = smem;          // 16384 floats (epilogue)

    const int tid  = threadIdx.x;
    const int bx   = blockIdx.x;
    const int b    = bx >> 6;
    const int rr   = bx & 63;
    const int bh   = rr >> 2;          // 0..15
    const int bw   = rr & 3;           // 0..3
    const int h0   = bh * (TN * 2);    // input row origin
    const int w0   = bw * (TM * 2);    // input col origin

    const int wv   = tid >> 6;         // wave id: xy (gemm) / c_local (transform) / k_local (epi)
    const int lane = tid & 63;
    const int k0   = (lane >> 3) << 3; // gemm: 8-k group
    const int t0   = (lane & 7) << 3;  // gemm: 8-t group
    const int tn   = lane >> 4;        // tile row 0..3
    const int tm   = lane & 15;        // tile col 0..15

    // transform threads (tid<512): channel = ch*CC + wv, tile (tn,tm)
    const float* xbase = x + ((size_t)(b * 64 + wv) * 130 + (h0 + 2 * tn)) * 130 + (w0 + 2 * tm);

    // U staging: 8192 floats per chunk = 2048 float4 ; thread stores float4 #tid and #tid+1024
    const int u_idx0 = tid;
    const int u_idx1 = tid + 1024;
    const int ug0 = (u_idx0 >> 7) * 1024 + (u_idx0 & 127);  // global float4 idx (xy*1024 + off4)
    const int ug1 = (u_idx1 >> 7) * 1024 + (u_idx1 & 127);
    const float4* U4 = (const float4*)U;

    float acc[8][8];
    #pragma unroll
    for (int i = 0; i < 8; ++i)
        #pragma unroll
        for (int j = 0; j < 8; ++j) acc[i][j] = 0.0f;

    // prefetch regs (chunk 0)
    float4 uf0 = U4[ug0];
    float4 uf1 = U4[ug1];
    float2 dn[4][2];
    if (tid < 512) {
        #pragma unroll
        for (int i = 0; i < 4; ++i) {
            dn[i][0] = *(const float2*)(xbase + i * 130);
            dn[i][1] = *(const float2*)(xbase + i * 130 + 2);
        }
    }

    #pragma unroll 1
    for (int ch = 0; ch < NCH; ++ch) {
        __syncthreads();   // previous GEMM done reading sU/sV
        // stage U chunk
        ((float4*)sU)[u_idx0] = uf0;
        ((float4*)sU)[u_idx1] = uf1;
        // input transform: V = B^T d B
        if (tid < 512) {
            float d[4][4];
            #pragma unroll
            for (int i = 0; i < 4; ++i) {
                d[i][0] = dn[i][0].x; d[i][1] = dn[i][0].y;
                d[i][2] = dn[i][1].x; d[i][3] = dn[i][1].y;
            }
            float s0[4], s1[4], s2[4], s3[4];
            #pragma unroll
            for (int j = 0; j < 4; ++j) {
                s0[j] = d[0][j] - d[2][j];
                s1[j] = d[1][j] + d[2][j];
                s2[j] = d[2][j] - d[1][j];
                s3[j] = d[1][j] - d[3][j];
            }
            const int vo = wv * 64 + lane;   // c_local*64 + t
            #define VROW(X, R)                                  \
                sV[((X)*4+0)*512 + vo] = R[0] - R[2];           \
                sV[((X)*4+1)*512 + vo] = R[1] + R[2];           \
                sV[((X)*4+2)*512 + vo] = R[2] - R[1];           \
                sV[((X)*4+3)*512 + vo] = R[1] - R[3];
            VROW(0, s0) VROW(1, s1) VROW(2, s2) VROW(3, s3)
            #undef VROW
        }
        __syncthreads();
        // prefetch next chunk (overlaps GEMM)
        if (ch < NCH - 1) {
            uf0 = U4[ug0 + (ch + 1) * 128];
            uf1 = U4[ug1 + (ch + 1) * 128];
            if (tid < 512) {
                const float* xn = xbase + (size_t)(ch + 1) * CC * 16900;
                #pragma unroll
                for (int i = 0; i < 4; ++i) {
                    dn[i][0] = *(const float2*)(xn + i * 130);
                    dn[i][1] = *(const float2*)(xn + i * 130 + 2);
                }
            }
        }
        // GEMM: wave wv owns xy=wv; lane tile 8k x 8t
        const float* Ub = sU + wv * 512 + k0;
        const float* Vb = sV + wv * 512 + t0;
        #pragma unroll 2
        for (int c = 0; c < CC; ++c) {
            float4 ua = *(const float4*)(Ub + c * 64);
            float4 ub = *(const float4*)(Ub + c * 64 + 4);
            float4 va = *(const float4*)(Vb + c * 64);
            float4 vb = *(const float4*)(Vb + c * 64 + 4);
            float uu[8] = { ua.x, ua.y, ua.z, ua.w, ub.x, ub.y, ub.z, ub.w };
            float vv[8] = { va.x, va.y, va.z, va.w, vb.x, vb.y, vb.z, vb.w };
            #pragma unroll
            for (int i = 0; i < 8; ++i)
                #pragma unroll
                for (int j = 0; j < 8; ++j)
                    acc[i][j] = fmaf(uu[i], vv[j], acc[i][j]);
        }
    }

    // epilogue: Y = A^T M A + bias, k in chunks of 16 through sM
    const int g = lane >> 3;
    #pragma unroll 1
    for (int kc = 0; kc < 4; ++kc) {
        __syncthreads();   // sM free (last GEMM / previous kc readers done)
        if (g == 2 * kc || g == 2 * kc + 1) {
            const int kk0 = k0 - kc * 16;          // 0 or 8
            float* mp = sM + wv * 1024 + kk0 * 64 + t0;
            #pragma unroll
            for (int i = 0; i < 8; ++i) {
                *(float4*)(mp + i * 64)     = make_float4(acc[i][0], acc[i][1], acc[i][2], acc[i][3]);
                *(float4*)(mp + i * 64 + 4) = make_float4(acc[i][4], acc[i][5], acc[i][6], acc[i][7]);
            }
        }
        __syncthreads();
        // k = kc*16 + wv, tile t = lane
        float m[16];
        #pragma unroll
        for (int xy = 0; xy < 16; ++xy) m[xy] = sM[xy * 1024 + wv * 64 + lane];
        float p0[4], p1[4];
        #pragma unroll
        for (int y = 0; y < 4; ++y) {
            p0[y] = m[y] + m[4 + y] + m[8 + y];
            p1[y] = m[4 + y] - m[8 + y] - m[12 + y];
        }
        const int k = kc * 16 + wv;
        const float bv = bias[k];
        const float y00 = p0[0] + p0[1] + p0[2] + bv;
        const float y01 = p0[1] - p0[2] - p0[3] + bv;
        const float y10 = p1[0] + p1[1] + p1[2] + bv;
        const float y11 = p1[1] - p1[2] - p1[3] + bv;
        const int oh = (bh * TN + tn) * 2;
        const int ow = (bw * TM + tm) * 2;
        float* op = out + ((size_t)(b * 64 + k) * 128 + oh) * 128 + ow;
        *(float2*)op         = make_float2(y00, y01);
        *(float2*)(op + 128) = make_float2(y10, y11);
    }
}

extern "C" void kernel_launch(void* const* d_in, const int* in_sizes, int n_in,
                              void* d_out, int out_size, void* d_ws, size_t ws_size,
                              hipStream_t stream) {
    const float* x    = (const float*)d_in[0];
    const float* w    = (const float*)d_in[1];
    const float* bias = (const float*)d_in[2];
    float* out = (float*)d_out;
    float* U   = (float*)d_ws;   // 256 KB
    wg_u_kernel<<<16, 256, 0, stream>>>(w, U);
    wg_main<<<512, 1024, 0, stream>>>(x, U, bias, out);
}

// Round 4
// 154.871 us; speedup vs baseline: 2.6707x; 1.0068x over previous
//
#include <hip/hip_runtime.h>

// Winograd F(2x2,3x3) fused conv. B=8, C=64, K=64, H=W=130 -> out 8x64x128x128 fp32.
// Single fused kernel: per C-chunk, waves 0-7 transform input tiles (V), waves
// 8-15 transform weights (U, recomputed per block - w is 147KB L2-resident),
// double-buffered LDS (one barrier per chunk), 16 xy-GEMMs on vector ALU
// (no fp32 MFMA on CDNA4), inverse transform + bias epilogue.
// R4: merge wg_u into main (1 launch), dbuf + 1 barrier/chunk (was 2).
//     R3: 79.7us main, VALUBusy 45%, ~44us barrier idle at 16 waves/CU.

#define CC 8      // C chunk
#define NCH 8     // 64/CC
#define TN 4      // tile rows per block
#define TM 16     // tile cols per block  (4x16 = 64 tiles -> 8x32 output pixels)

__global__ __launch_bounds__(1024, 4) void wg_main(
    const float* __restrict__ x, const float* __restrict__ w,
    const float* __restrict__ bias, float* __restrict__ out)
{
    // 128KB LDS: buf[2] x { sU[16][CC][64] , sV[16][CC][64] } ; epilogue sM aliases buf0
    __shared__ float smem[32768];
    float* sM = smem;          // 16384 floats (epilogue, aliases buf0)

    const int tid  = threadIdx.x;
    const int bx   = blockIdx.x;
    const int b    = bx >> 6;
    const int rr   = bx & 63;
    const int bh   = rr >> 2;          // 0..15
    const int bw   = rr & 3;           // 0..3
    const int h0   = bh * (TN * 2);    // input row origin
    const int w0   = bw * (TM * 2);    // input col origin

    const int wv   = tid >> 6;         // wave id
    const int lane = tid & 63;
    const int k0   = (lane >> 3) << 3; // gemm: 8-k group
    const int t0   = (lane & 7) << 3;  // gemm: 8-t group
    const int tn   = lane >> 4;        // tile row 0..3
    const int tm   = lane & 15;        // tile col 0..15

    // V-transform threads (tid<512): channel = ch*CC + wv, tile (tn,tm)
    const float* xbase = x + ((size_t)(b * 64 + wv) * 130 + (h0 + 2 * tn)) * 130 + (w0 + 2 * tm);
    // U-transform threads (tid>=512): k = lane, c = ch*CC + (wv-8)
    const int wu = wv - 8;
    const float* wbase = w + ((size_t)(lane * 64) + wu) * 9;   // + ch*CC*9 per chunk

    float acc[8][8];
    #pragma unroll
    for (int i = 0; i < 8; ++i)
        #pragma unroll
        for (int j = 0; j < 8; ++j) acc[i][j] = 0.0f;

    // prefetch regs (chunk 0)
    float2 dn[4][2];
    float wr[9];
    if (tid < 512) {
        #pragma unroll
        for (int i = 0; i < 4; ++i) {
            dn[i][0] = *(const float2*)(xbase + i * 130);
            dn[i][1] = *(const float2*)(xbase + i * 130 + 2);
        }
    } else {
        #pragma unroll
        for (int i = 0; i < 9; ++i) wr[i] = wbase[i];
    }

    #pragma unroll 1
    for (int ch = 0; ch < NCH; ++ch) {
        float* bs = smem + (ch & 1) * 16384;   // sU at bs, sV at bs+8192
        if (tid < 512) {
            // input transform: V = B^T d B -> sV
            float d[4][4];
            #pragma unroll
            for (int i = 0; i < 4; ++i) {
                d[i][0] = dn[i][0].x; d[i][1] = dn[i][0].y;
                d[i][2] = dn[i][1].x; d[i][3] = dn[i][1].y;
            }
            float s0[4], s1[4], s2[4], s3[4];
            #pragma unroll
            for (int j = 0; j < 4; ++j) {
                s0[j] = d[0][j] - d[2][j];
                s1[j] = d[1][j] + d[2][j];
                s2[j] = d[2][j] - d[1][j];
                s3[j] = d[1][j] - d[3][j];
            }
            float* sV = bs + 8192;
            const int vo = wv * 64 + lane;   // c_local*64 + t
            #define VROW(X, R)                                  \
                sV[((X)*4+0)*512 + vo] = R[0] - R[2];           \
                sV[((X)*4+1)*512 + vo] = R[1] + R[2];           \
                sV[((X)*4+2)*512 + vo] = R[2] - R[1];           \
                sV[((X)*4+3)*512 + vo] = R[1] - R[3];
            VROW(0, s0) VROW(1, s1) VROW(2, s2) VROW(3, s3)
            #undef VROW
        } else {
            // weight transform: U = G w G^T -> sU
            float t0r[3] = { wr[0], wr[1], wr[2] };
            float t1r[3] = { 0.5f*(wr[0]+wr[3]+wr[6]), 0.5f*(wr[1]+wr[4]+wr[7]), 0.5f*(wr[2]+wr[5]+wr[8]) };
            float t2r[3] = { 0.5f*(wr[0]-wr[3]+wr[6]), 0.5f*(wr[1]-wr[4]+wr[7]), 0.5f*(wr[2]-wr[5]+wr[8]) };
            float t3r[3] = { wr[6], wr[7], wr[8] };
            const int uo = wu * 64 + lane;   // c_local*64 + k
            #define UROW(X, R)                                          \
                bs[((X)*4+0)*512 + uo] = R[0];                          \
                bs[((X)*4+1)*512 + uo] = 0.5f*(R[0] + R[1] + R[2]);     \
                bs[((X)*4+2)*512 + uo] = 0.5f*(R[0] - R[1] + R[2]);     \
                bs[((X)*4+3)*512 + uo] = R[2];
            UROW(0, t0r) UROW(1, t1r) UROW(2, t2r) UROW(3, t3r)
            #undef UROW
        }
        __syncthreads();
        // prefetch next chunk (overlaps GEMM)
        if (ch < NCH - 1) {
            if (tid < 512) {
                const float* xn = xbase + (size_t)(ch + 1) * CC * 16900;
                #pragma unroll
                for (int i = 0; i < 4; ++i) {
                    dn[i][0] = *(const float2*)(xn + i * 130);
                    dn[i][1] = *(const float2*)(xn + i * 130 + 2);
                }
            } else {
                const float* wn = wbase + (size_t)(ch + 1) * CC * 9;
                #pragma unroll
                for (int i = 0; i < 9; ++i) wr[i] = wn[i];
            }
        }
        // GEMM: wave wv owns xy=wv; lane tile 8k x 8t
        const float* Ub = bs + wv * 512 + k0;
        const float* Vb = bs + 8192 + wv * 512 + t0;
        #pragma unroll 2
        for (int c = 0; c < CC; ++c) {
            float4 ua = *(const float4*)(Ub + c * 64);
            float4 ub = *(const float4*)(Ub + c * 64 + 4);
            float4 va = *(const float4*)(Vb + c * 64);
            float4 vb = *(const float4*)(Vb + c * 64 + 4);
            float uu[8] = { ua.x, ua.y, ua.z, ua.w, ub.x, ub.y, ub.z, ub.w };
            float vv[8] = { va.x, va.y, va.z, va.w, vb.x, vb.y, vb.z, vb.w };
            #pragma unroll
            for (int i = 0; i < 8; ++i)
                #pragma unroll
                for (int j = 0; j < 8; ++j)
                    acc[i][j] = fmaf(uu[i], vv[j], acc[i][j]);
        }
    }

    // epilogue: Y = A^T M A + bias, k in chunks of 16 through sM (aliases buf0;
    // last GEMM read buf1, first barrier below fences all readers)
    const int g = lane >> 3;
    #pragma unroll 1
    for (int kc = 0; kc < 4; ++kc) {
        __syncthreads();   // sM free (last GEMM / previous kc readers done)
        if (g == 2 * kc || g == 2 * kc + 1) {
            const int kk0 = k0 - kc * 16;          // 0 or 8
            float* mp = sM + wv * 1024 + kk0 * 64 + t0;
            #pragma unroll
            for (int i = 0; i < 8; ++i) {
                *(float4*)(mp + i * 64)     = make_float4(acc[i][0], acc[i][1], acc[i][2], acc[i][3]);
                *(float4*)(mp + i * 64 + 4) = make_float4(acc[i][4], acc[i][5], acc[i][6], acc[i][7]);
            }
        }
        __syncthreads();
        // k = kc*16 + wv, tile t = lane
        float m[16];
        #pragma unroll
        for (int xy = 0; xy < 16; ++xy) m[xy] = sM[xy * 1024 + wv * 64 + lane];
        float p0[4], p1[4];
        #pragma unroll
        for (int y = 0; y < 4; ++y) {
            p0[y] = m[y] + m[4 + y] + m[8 + y];
            p1[y] = m[4 + y] - m[8 + y] - m[12 + y];
        }
        const int k = kc * 16 + wv;
        const float bv = bias[k];
        const float y00 = p0[0] + p0[1] + p0[2] + bv;
        const float y01 = p0[1] - p0[2] - p0[3] + bv;
        const float y10 = p1[0] + p1[1] + p1[2] + bv;
        const float y11 = p1[1] - p1[2] - p1[3] + bv;
        const int oh = (bh * TN + tn) * 2;
        const int ow = (bw * TM + tm) * 2;
        float* op = out + ((size_t)(b * 64 + k) * 128 + oh) * 128 + ow;
        *(float2*)op         = make_float2(y00, y01);
        *(float2*)(op + 128) = make_float2(y10, y11);
    }
}

extern "C" void kernel_launch(void* const* d_in, const int* in_sizes, int n_in,
                              void* d_out, int out_size, void* d_ws, size_t ws_size,
                              hipStream_t stream) {
    const float* x    = (const float*)d_in[0];
    const float* w    = (const float*)d_in[1];
    const float* bias = (const float*)d_in[2];
    float* out = (float*)d_out;
    wg_main<<<512, 1024, 0, stream>>>(x, w, bias, out);
}

// Round 5
// 128.950 us; speedup vs baseline: 3.2076x; 1.2010x over previous
//
#include <hip/hip_runtime.h>
#include <hip/hip_bf16.h>

// Winograd F(2x2,3x3) conv via split-bf16 MFMA. B=8,C=64,K=64 -> out 8x64x128x128 fp32.
// wg_u: U = GwG^T, split hi/lo bf16, stored in d_ws in mfma-A-fragment-linear layout.
// wg_main: per block (b, 4x16 tile patch = 64 tiles): transform x -> V fp32 in LDS
//   [16xy][64t][36c-pad]; 16 waves (wave=xy) run 64x64x64 GEMM as 2 K-steps of
//   mfma_f32_16x16x32_bf16 with D = UhVh + UhVl + UlVh (fp32 acc; err ~2^-17).
//   A(U) streamed global->reg (L2-resident); B(V) read fp32 from LDS, cvt in-reg.
// R5: replaces fp32 VALU GEMM (LDS-pipe-bound, 83us, VALUBusy 47%).

typedef __attribute__((ext_vector_type(8))) short short8;
typedef __attribute__((ext_vector_type(4))) float f32x4;

#define CPAD 36                 // c-dim pad (16B-aligned frag reads, bank spread)
#define LDS_BYTES (16*64*CPAD*4)   // 147456 B = 144 KB (V fp32)

__device__ __forceinline__ unsigned short f2bf(float f) {
    unsigned u = __float_as_uint(f);
    unsigned r = (u + 0x7FFF + ((u >> 16) & 1)) >> 16;   // RNE
    return (unsigned short)r;
}

// U frag layout: f = ((xy*2+ks)*4+mt)*2+hl ; ushort[f*512 + lane*8 + j]
// A-frag lane l holds U[k = mt*16 + (l&15)][c = ks*32 + (l>>4)*8 + j]
__global__ void wg_u(const float* __restrict__ w, unsigned short* __restrict__ Uf) {
    int tid = blockIdx.x * blockDim.x + threadIdx.x;  // 4096 = K*C
    int k = tid & 63, c = tid >> 6;
    const float* wp = w + (k * 64 + c) * 9;
    float g[9];
    #pragma unroll
    for (int i = 0; i < 9; ++i) g[i] = wp[i];
    float t[4][3];
    #pragma unroll
    for (int j = 0; j < 3; ++j) {
        t[0][j] = g[j];
        t[1][j] = 0.5f * (g[j] + g[3 + j] + g[6 + j]);
        t[2][j] = 0.5f * (g[j] - g[3 + j] + g[6 + j]);
        t[3][j] = g[6 + j];
    }
    const int ks   = c >> 5;
    const int mt   = k >> 4;
    const int lane = (k & 15) + 16 * ((c >> 3) & 3);
    const int j    = c & 7;
    #pragma unroll
    for (int xr = 0; xr < 4; ++xr) {
        float a = t[xr][0], b = t[xr][1], cc = t[xr][2];
        float u4[4] = { a, 0.5f * (a + b + cc), 0.5f * (a - b + cc), cc };
        #pragma unroll
        for (int yr = 0; yr < 4; ++yr) {
            int xy = xr * 4 + yr;
            float uv = u4[yr];
            unsigned short h = f2bf(uv);
            float hf = __uint_as_float(((unsigned)h) << 16);
            unsigned short l = f2bf(uv - hf);
            int fh = ((xy * 2 + ks) * 4 + mt) * 2;
            Uf[(fh + 0) * 512 + lane * 8 + j] = h;
            Uf[(fh + 1) * 512 + lane * 8 + j] = l;
        }
    }
}

// cvt 8 fp32 -> bf16 hi/lo frags (pair cvt -> v_cvt_pk_bf16_f32)
__device__ __forceinline__ void cvt_frag(f32x4 a, f32x4 b, short8& h8, short8& l8) {
    union { short8 s; unsigned u[4]; } H, L;
    float v0[4] = { a[0], a[2], b[0], b[2] };
    float v1[4] = { a[1], a[3], b[1], b[3] };
    #pragma unroll
    for (int p = 0; p < 4; ++p) {
        __hip_bfloat162 hb = __float22bfloat162_rn(make_float2(v0[p], v1[p]));
        unsigned hu; __builtin_memcpy(&hu, &hb, 4);
        float h0 = __uint_as_float(hu << 16);
        float h1 = __uint_as_float(hu & 0xFFFF0000u);
        __hip_bfloat162 lb = __float22bfloat162_rn(make_float2(v0[p] - h0, v1[p] - h1));
        unsigned lu; __builtin_memcpy(&lu, &lb, 4);
        H.u[p] = hu; L.u[p] = lu;
    }
    h8 = H.s; l8 = L.s;
}

__global__ __launch_bounds__(1024, 4) void wg_main(
    const float* __restrict__ x, const unsigned short* __restrict__ Uf,
    const float* __restrict__ bias, float* __restrict__ out)
{
    extern __shared__ float smem[];     // V[16 xy][64 t][36 c] fp32; epilogue sM[16][16][65]

    const int tid  = threadIdx.x;
    const int bx   = blockIdx.x;
    const int b    = bx >> 6;
    const int rr   = bx & 63;
    const int bh   = rr >> 2;           // 0..15
    const int bw   = rr & 3;            // 0..3
    const int h0   = bh * 8;
    const int w0   = bw * 32;

    const int wv   = tid >> 6;          // wave = xy
    const int lane = tid & 63;

    f32x4 acc[4][4];
    #pragma unroll
    for (int i = 0; i < 4; ++i)
        #pragma unroll
        for (int j = 0; j < 4; ++j) acc[i][j] = f32x4{0.f, 0.f, 0.f, 0.f};

    #pragma unroll 1
    for (int ch = 0; ch < 2; ++ch) {
        if (ch) __syncthreads();        // GEMM of prev chunk done reading V
        // ---- produce V for c = ch*32 .. +31 (2 units per thread) ----
        #pragma unroll
        for (int uu = 0; uu < 2; ++uu) {
            const int u   = (tid >> 6) + uu * 16;      // 0..31
            const int c_l = (u & 3) * 8 + (lane >> 3); // 0..31
            const int t   = (u >> 2) * 8 + (lane & 7); // 0..63
            const int c   = ch * 32 + c_l;
            const int tn  = t >> 4, tm = t & 15;
            const float* xp = x + ((size_t)(b * 64 + c) * 130 + (h0 + 2 * tn)) * 130 + (w0 + 2 * tm);
            float d[4][4];
            #pragma unroll
            for (int i = 0; i < 4; ++i) {
                float2 a0 = *(const float2*)(xp + i * 130);
                float2 a1 = *(const float2*)(xp + i * 130 + 2);
                d[i][0] = a0.x; d[i][1] = a0.y; d[i][2] = a1.x; d[i][3] = a1.y;
            }
            float s0[4], s1[4], s2[4], s3[4];
            #pragma unroll
            for (int j = 0; j < 4; ++j) {
                s0[j] = d[0][j] - d[2][j];
                s1[j] = d[1][j] + d[2][j];
                s2[j] = d[2][j] - d[1][j];
                s3[j] = d[1][j] - d[3][j];
            }
            float* vp = smem + t * CPAD + c_l;   // + xy*2304
            #define VROW(X, R)                                   \
                vp[((X)*4+0)*(64*CPAD)... 
            #undef VROW
            // (expanded below without macro to keep indexing explicit)
            const int base = t * CPAD + c_l;
            #pragma unroll
            for (int xr = 0; xr < 4; ++xr) {
                float* rp;
                float r0, r1, r2, r3;
                const float* S = (xr == 0) ? s0 : (xr == 1) ? s1 : (xr == 2) ? s2 : s3;
                r0 = S[0] - S[2];
                r1 = S[1] + S[2];
                r2 = S[2] - S[1];
                r3 = S[1] - S[3];
                smem[(xr * 4 + 0) * (64 * CPAD) + base] = r0;
                smem[(xr * 4 + 1) * (64 * CPAD) + base] = r1;
                smem[(xr * 4 + 2) * (64 * CPAD) + base] = r2;
                smem[(xr * 4 + 3) * (64 * CPAD) + base] = r3;
                (void)rp;
            }
        }
        __syncthreads();
        // ---- GEMM K-step (ks = ch): 48 mfma ----
        // A frags: 8 coalesced global loads (bf16, pre-split, L2-resident)
        const unsigned short* Ab = Uf + ((size_t)(wv * 2 + ch) * 8) * 512 + lane * 8;
        short8 ah[4], al[4];
        #pragma unroll
        for (int mt = 0; mt < 4; ++mt) {
            ah[mt] = *(const short8*)(Ab + (mt * 2 + 0) * 512);
            al[mt] = *(const short8*)(Ab + (mt * 2 + 1) * 512);
        }
        const int brow = wv * (64 * CPAD) + (lane & 15) * CPAD + (lane >> 4) * 8;
        #pragma unroll
        for (int nt = 0; nt < 4; ++nt) {
            f32x4 p0 = *(const f32x4*)(smem + brow + nt * 16 * CPAD);
            f32x4 p1 = *(const f32x4*)(smem + brow + nt * 16 * CPAD + 4);
            short8 bhf, blf;
            cvt_frag(p0, p1, bhf, blf);
            #pragma unroll
            for (int mt = 0; mt < 4; ++mt) {
                acc[mt][nt] = __builtin_amdgcn_mfma_f32_16x16x32_bf16(ah[mt], bhf, acc[mt][nt], 0, 0, 0);
                acc[mt][nt] = __builtin_amdgcn_mfma_f32_16x16x32_bf16(ah[mt], blf, acc[mt][nt], 0, 0, 0);
                acc[mt][nt] = __builtin_amdgcn_mfma_f32_16x16x32_bf16(al[mt], bhf, acc[mt][nt], 0, 0, 0);
            }
        }
    }

    // ---- epilogue: Y = A^T M A + bias, k in 4 chunks of 16 via sM[16xy][16k][65] ----
    float* sM = smem;
    #pragma unroll
    for (int kc = 0; kc < 4; ++kc) {
        __syncthreads();    // previous readers (GEMM or prior kc) done
        #pragma unroll
        for (int nt = 0; nt < 4; ++nt)
            #pragma unroll
            for (int r = 0; r < 4; ++r)
                sM[wv * 1040 + ((lane >> 4) * 4 + r) * 65 + nt * 16 + (lane & 15)] = acc[kc][nt][r];
        __syncthreads();
        float m[16];
        #pragma unroll
        for (int xy = 0; xy < 16; ++xy) m[xy] = sM[xy * 1040 + wv * 65 + lane];
        float p0[4], p1[4];
        #pragma unroll
        for (int y = 0; y < 4; ++y) {
            p0[y] = m[y] + m[4 + y] + m[8 + y];
            p1[y] = m[4 + y] - m[8 + y] - m[12 + y];
        }
        const int k  = kc * 16 + wv;
        const float bv = bias[k];
        const float y00 = p0[0] + p0[1] + p0[2] + bv;
        const float y01 = p0[1] - p0[2] - p0[3] + bv;
        const float y10 = p1[0] + p1[1] + p1[2] + bv;
        const float y11 = p1[1] - p1[2] - p1[3] + bv;
        const int tn = lane >> 4, tm = lane & 15;
        const int oh = (bh * 4 + tn) * 2;
        const int ow = (bw * 16 + tm) * 2;
        float* op = out + ((size_t)(b * 64 + k) * 128 + oh) * 128 + ow;
        *(float2*)op         = make_float2(y00, y01);
        *(float2*)(op + 128) = make_float2(y10, y11);
    }
}

extern "C" void kernel_launch(void* const* d_in, const int* in_sizes, int n_in,
                              void* d_out, int out_size, void* d_ws, size_t ws_size,
                              hipStream_t stream) {
    const float* x    = (const float*)d_in[0];
    const float* w    = (const float*)d_in[1];
    const float* bias = (const float*)d_in[2];
    float* out = (float*)d_out;
    unsigned short* Uf = (unsigned short*)d_ws;   // 256 KB frag-layout U (hi/lo bf16)
    static_assert(LDS_BYTES == 147456, "lds size");
    hipFuncSetAttribute((const void*)wg_main, hipFuncAttributeMaxDynamicSharedMemorySize, LDS_BYTES);
    wg_u<<<16, 256, 0, stream>>>(w, Uf);
    wg_main<<<512, 1024, LDS_BYTES, stream>>>(x, Uf, bias, out);
}